// Round 5
// baseline (16249.800 us; speedup 1.0000x reference)
//
#include <hip/hip_runtime.h>
#include <hip/hip_bf16.h>
#include <stdint.h>

#define HDIM 1024
#define GDIM 5120
#define NWG_SER 128
#define TPB_SER 256
#define NAN_U 0x7FC00000u
#define FLAG_WIN 64

typedef __attribute__((ext_vector_type(8))) short v8s;
typedef __attribute__((ext_vector_type(4))) float v4f;

// ---------------- workspace layout (bytes) ----------------
constexpr long long PRE_OFF   = 0;                              // f32 [2048][5120] gate pre-sums for reduces
constexpr long long LEAFG_OFF = PRE_OFF   + 2048LL * 5120 * 4;  // f32 [2048][5120] leaf gates
constexpr long long DUMP_OFF  = LEAFG_OFF + 2048LL * 5120 * 4;  // f32 [8192] scratch dump row
constexpr long long XSBF_OFF  = DUMP_OFF  + 8192LL * 4;         // bf16 [4096][1024]
constexpr long long WIH_OFF   = XSBF_OFF  + 4096LL * 1024 * 2;  // bf16 [5120][1024]
constexpr long long WLHH_OFF  = WIH_OFF   + 5120LL * 1024 * 2;
constexpr long long WRHH_OFF  = WLHH_OFF  + 5120LL * 1024 * 2;
constexpr long long HBF_OFF   = WRHH_OFF  + 5120LL * 1024 * 2;  // bf16 [4096][1024] per-node h (GEMM input)
constexpr long long B3_OFF    = HBF_OFF   + 4096LL * 1024 * 2;  // f32 [5120]
constexpr long long PLAN_OFF  = B3_OFF    + 5120LL * 4;         // int [26688]
constexpr long long FLAG_OFF  = PLAN_OFF  + 26688LL * 4;        // u8 [64][512] windowed step flags
// total ~126.2 MiB (+41KB vs round-3 proven footprint)

// plan array offsets (int units)
constexpr int P_TRED = 0, P_LNODE = 2048, P_RNODE = 4096, P_FLAGS = 6144,
              P_TLEAF = 8192, P_DEST1 = 10240, P_NODER = 14336, P_DESTR = 16384,
              P_NODEL = 18432, P_DESTL = 20480, P_CNT = 22528,
              P_LRX = 22592, P_RRX = 24640;
// counts: [0]=nred, [1]=activeR rows, [2]=activeL rows, [3]=n_nodes (G1 active rows)
// FLAGS packing: bit0 = left child is reduce; bit1 = right child is reduce;
//                bits2-3 = lidx (stack slot), bits4-5 = ridx, bits6-7 = pos.
// P_LRX/P_RRX: reduce index of left/right child when it is a reduce node.

// f32-element bases inside ws
constexpr int PRE_E   = 0;
constexpr int LEAFG_E = (int)(LEAFG_OFF / 4);
constexpr int DUMP_E  = (int)(DUMP_OFF / 4);

static __device__ __forceinline__ float sigf(float x) { return 1.0f / (1.0f + __expf(-x)); }
static __device__ __forceinline__ float tanh_f(float x) {
  if (x > 15.0f) return 1.0f;
  if (x < -15.0f) return -1.0f;
  float e = __expf(2.0f * x);
  return (e - 1.0f) / (e + 1.0f);
}
static __device__ __forceinline__ unsigned short f2bf(float x) {
  __hip_bfloat16 h = __float2bfloat16(x);
  union { __hip_bfloat16 h; unsigned short u; } cv;
  cv.h = h;
  return cv.u;
}

// ---------------- plan: simulate the stack, build scatter lists ----------------
__global__ void plan_kernel(const int* __restrict__ ops, int n_nodes, int* __restrict__ plan) {
  __shared__ int sops[4096];
  __shared__ int red_of[4096];
  for (int i = threadIdx.x; i < n_nodes; i += 256) sops[i] = ops[i];
  __syncthreads();
  if (threadIdx.x != 0) return;
  int stack[4] = {0, 0, 0, 0};
  int ptr = 0, nred = 0, nleaf = 0, nR = 0, nL = 0;
  for (int t = 0; t < n_nodes; ++t) {
    int op = sops[t];
    if (op == 1) {
      int ridx = min(max(ptr - 1, 0), 3);
      int lidx = min(max(ptr - 2, 0), 3);
      int ln = stack[lidx], rn = stack[ridx];
      int r = nred++;
      plan[P_TRED + r] = t;
      plan[P_LNODE + r] = ln;
      plan[P_RNODE + r] = rn;
      int pos = min(max(ptr - 2, 0), 3);
      int lred = (sops[ln] == 1) ? 1 : 0;
      int rred = (sops[rn] == 1) ? 2 : 0;
      plan[P_FLAGS + r] = lred | rred | (lidx << 2) | (ridx << 4) | (pos << 6);
      plan[P_LRX + r] = lred ? red_of[ln] : 0;
      plan[P_RRX + r] = rred ? red_of[rn] : 0;
      plan[P_DEST1 + t] = PRE_E + r * GDIM;
      if (!rred) { plan[P_NODER + nR] = rn; plan[P_DESTR + nR] = PRE_E + r * GDIM; nR++; }
      if (!lred) { plan[P_NODEL + nL] = ln; plan[P_DESTL + nL] = PRE_E + r * GDIM; nL++; }
      red_of[t] = r;
      stack[pos] = t;
      ptr = (ptr - 2) + 1;
    } else {
      int li = nleaf++;
      plan[P_TLEAF + li] = t;
      plan[P_DEST1 + t] = LEAFG_E + li * GDIM;
      stack[min(max(ptr, 0), 3)] = t;
      ptr = ptr + 1;
    }
  }
  for (int i = n_nodes; i < 4096; ++i) plan[P_DEST1 + i] = DUMP_E;
  for (int i = nR; i < 2048; ++i) { plan[P_NODER + i] = 0; plan[P_DESTR + i] = DUMP_E; }
  for (int i = nL; i < 2048; ++i) { plan[P_NODEL + i] = 0; plan[P_DESTL + i] = DUMP_E; }
  plan[P_CNT + 0] = nred;
  plan[P_CNT + 1] = nR;
  plan[P_CNT + 2] = nL;
  plan[P_CNT + 3] = n_nodes;
}

// ---------------- NaN-sentinel init for reduce-node h rows ----------------
__global__ void init_nan_kernel(const int* __restrict__ ops, int n_nodes,
                                unsigned int* __restrict__ hsu) {
  const int t = blockIdx.x;
  if (t >= n_nodes || ops[t] != 1) return;
  uint4 nv = make_uint4(NAN_U, NAN_U, NAN_U, NAN_U);
  *(uint4*)(hsu + (long long)t * HDIM + threadIdx.x * 4) = nv;
}

// ---------------- f32 -> bf16 convert (zero-pads beyond nsrc) ----------------
__global__ void cvt_bf16_kernel(const float* __restrict__ src, unsigned short* __restrict__ dst,
                                int ntotal, int nsrc) {
  int i = (blockIdx.x * 256 + threadIdx.x) * 4;
  if (i >= ntotal) return;
  float4 v = make_float4(0.f, 0.f, 0.f, 0.f);
  if (i < nsrc) v = *(const float4*)(src + i);
  ushort4 o;
  o.x = f2bf(v.x); o.y = f2bf(v.y); o.z = f2bf(v.z); o.w = f2bf(v.w);
  *(ushort4*)(dst + i) = o;
}

__global__ void b3_kernel(const float* __restrict__ a, const float* __restrict__ b,
                          const float* __restrict__ c, float* __restrict__ o) {
  int i = blockIdx.x * 256 + threadIdx.x;
  if (i < GDIM) o[i] = a[i] + b[i] + c[i];
}

// ---------------- NT MFMA GEMM with per-row scatter destinations ----------------
template <int GATHER, int ACCUM>
__global__ __launch_bounds__(256, 1) void gemm_bt(
    const unsigned short* __restrict__ A, const unsigned short* __restrict__ B,
    const int* __restrict__ gidx, const int* __restrict__ dest,
    float* __restrict__ wsf, const float* __restrict__ b3,
    const int* __restrict__ activeRows) {
  if ((int)blockIdx.x * 128 >= *activeRows) return;
  __shared__ unsigned short As[128 * 32];
  __shared__ unsigned short Bs[128 * 32];
  const int tid = threadIdx.x;
  const int w = tid >> 6, l = tid & 63;
  const int tm = blockIdx.x, tn = blockIdx.y;
  const int q0 = w * 2, q1 = w * 2 + 1;
  const int r0 = q0 * 16 + (l >> 2), r1 = q1 * 16 + (l >> 2);
  const int ck = (l & 3) * 8;
  int ga0 = tm * 128 + r0, ga1 = tm * 128 + r1;
  if (GATHER) { ga0 = gidx[ga0]; ga1 = gidx[ga1]; }
  const unsigned short* ap0 = A + (long long)ga0 * HDIM + ck;
  const unsigned short* ap1 = A + (long long)ga1 * HDIM + ck;
  const unsigned short* bp0 = B + (long long)(tn * 128 + r0) * HDIM + ck;
  const unsigned short* bp1 = B + (long long)(tn * 128 + r1) * HDIM + ck;
  uint4* asd0 = (uint4*)(As + q0 * 512) + l;
  uint4* asd1 = (uint4*)(As + q1 * 512) + l;
  uint4* bsd0 = (uint4*)(Bs + q0 * 512) + l;
  uint4* bsd1 = (uint4*)(Bs + q1 * 512) + l;
  const int wr = w >> 1, wc = w & 1;
  const int lrow = l & 15, lq = l >> 4;
  const unsigned short* Ard = As + (wr * 64 + lrow) * 32 + lq * 8;
  const unsigned short* Brd = Bs + (wc * 64 + lrow) * 32 + lq * 8;
  v4f acc[4][4];
#pragma unroll
  for (int m = 0; m < 4; ++m)
#pragma unroll
    for (int n = 0; n < 4; ++n) acc[m][n] = (v4f){0.f, 0.f, 0.f, 0.f};
  for (int kb = 0; kb < 32; ++kb) {
    const int ko = kb * 32;
    uint4 a0 = *(const uint4*)(ap0 + ko);
    uint4 a1 = *(const uint4*)(ap1 + ko);
    uint4 b0 = *(const uint4*)(bp0 + ko);
    uint4 b1 = *(const uint4*)(bp1 + ko);
    __syncthreads();
    *asd0 = a0; *asd1 = a1; *bsd0 = b0; *bsd1 = b1;
    __syncthreads();
    v8s af[4], bfr[4];
#pragma unroll
    for (int m = 0; m < 4; ++m) af[m] = *(const v8s*)(Ard + m * 512);
#pragma unroll
    for (int n = 0; n < 4; ++n) bfr[n] = *(const v8s*)(Brd + n * 512);
#pragma unroll
    for (int m = 0; m < 4; ++m)
#pragma unroll
      for (int n = 0; n < 4; ++n)
        acc[m][n] = __builtin_amdgcn_mfma_f32_16x16x32_bf16(af[m], bfr[n], acc[m][n], 0, 0, 0);
  }
#pragma unroll
  for (int m = 0; m < 4; ++m) {
#pragma unroll
    for (int jj = 0; jj < 4; ++jj) {
      const int arow = tm * 128 + wr * 64 + m * 16 + lq * 4 + jj;
      const int doff = dest[arow];
#pragma unroll
      for (int n = 0; n < 4; ++n) {
        const int col = tn * 128 + wc * 64 + n * 16 + lrow;
        float v = acc[m][n][jj];
        if (ACCUM) wsf[doff + col] += v;
        else wsf[doff + col] = v + b3[col];
      }
    }
  }
}

// ---------------- leaf (shift) cell: gates -> h,c with zero hidden state ----------------
__global__ void leaf_cell(const float* __restrict__ leafg, const int* __restrict__ plan,
                          float* __restrict__ hs, float* __restrict__ cs,
                          unsigned short* __restrict__ hbf) {
  const int li = blockIdx.x;
  const int j = threadIdx.x * 4;
  const float* row = leafg + (long long)li * GDIM;
  float4 gi = *(const float4*)(row + j);
  float4 gg = *(const float4*)(row + 3 * HDIM + j);
  float4 go = *(const float4*)(row + 4 * HDIM + j);
  const int t = plan[P_TLEAF + li];
  float4 yc, yh;
  yc.x = sigf(gi.x) * tanh_f(gg.x); yc.y = sigf(gi.y) * tanh_f(gg.y);
  yc.z = sigf(gi.z) * tanh_f(gg.z); yc.w = sigf(gi.w) * tanh_f(gg.w);
  yh.x = sigf(go.x) * tanh_f(yc.x); yh.y = sigf(go.y) * tanh_f(yc.y);
  yh.z = sigf(go.z) * tanh_f(yc.z); yh.w = sigf(go.w) * tanh_f(yc.w);
  *(float4*)(hs + (long long)t * HDIM + j) = yh;
  *(float4*)(cs + (long long)t * HDIM + j) = yc;
  ushort4 hb;
  hb.x = f2bf(yh.x); hb.y = f2bf(yh.y); hb.z = f2bf(yh.z); hb.w = f2bf(yh.w);
  *(ushort4*)(hbf + (long long)t * HDIM + j) = hb;
}

// ---------------- serial reduce chain v5: wave-autonomous, barrier-free ----------------
// 512 waves (128 WG x 256t). Wave wid owns channels {2*wid, 2*wid+1}: 10 weight
// rows in regs (lane l holds cols q*64+l). Handoff: h 8B store -> vmcnt(0) ->
// 1B flag; consumers spin on the 512B/step flag row (windowed, NaN backstop on
// data makes flags purely advisory). No __syncthreads in the loop.
__global__ __launch_bounds__(TPB_SER, 1) void serial_chain(
    const float* __restrict__ Wl, const float* __restrict__ Wr,
    const float* __restrict__ pre, const int* __restrict__ plan,
    float* __restrict__ hs, float* __restrict__ cs,
    unsigned char* __restrict__ flags) {
  const int wg = blockIdx.x;
  const int tid = threadIdx.x;
  const int w = tid >> 6, l = tid & 63;
  const int wid = wg * 4 + w;
  const int ch0 = wid * 2;
  __shared__ int s_t[2048], s_ln[2048], s_rn[2048], s_fl[2048], s_lrx[2048], s_rrx[2048];
  const int nred = plan[P_CNT + 0];
  for (int i = tid; i < nred; i += TPB_SER) {
    s_t[i] = plan[P_TRED + i];
    s_ln[i] = plan[P_LNODE + i];
    s_rn[i] = plan[P_RNODE + i];
    s_fl[i] = plan[P_FLAGS + i];
    s_lrx[i] = plan[P_LRX + i];
    s_rrx[i] = plan[P_RRX + i];
  }
  // weights: k = c*5 + g -> row g*1024 + ch0 + c, lane l holds cols q*64+l
  float wreg[10][16];
#pragma unroll
  for (int c = 0; c < 2; ++c)
#pragma unroll
    for (int g = 0; g < 5; ++g) {
      const float* wp = Wl + (long long)(g * HDIM + ch0 + c) * HDIM + l;
#pragma unroll
      for (int q = 0; q < 16; ++q) wreg[c * 5 + g][q] = wp[q * 64];
    }
  float cst0 = 0.f, cst1 = 0.f, cst2 = 0.f, cst3 = 0.f;  // per-lane c stack (lanes 0/1)
  __syncthreads();
  unsigned int* fu = (unsigned int*)flags;
  for (int r = 0; r < nred; ++r) {
    const int t = s_t[r], ln = s_ln[r], rn = s_rn[r], fl = s_fl[r];
    // early-issue: pre slice + leaf-child c (latency hides under the spin)
    float pv0 = 0.f, pv1 = 0.f, pv2 = 0.f, pv3 = 0.f, pv4 = 0.f, lcv = 0.f, rcv = 0.f;
    if (l < 2) {
      const float* pr = pre + (long long)r * GDIM + ch0 + l;
      pv0 = pr[0]; pv1 = pr[HDIM]; pv2 = pr[2 * HDIM]; pv3 = pr[3 * HDIM]; pv4 = pr[4 * HDIM];
      if (!(fl & 1)) lcv = cs[(long long)ln * HDIM + ch0 + l];
      if (!(fl & 2)) rcv = cs[(long long)rn * HDIM + ch0 + l];
    }
    {
      const int lidx = (fl >> 2) & 3, ridx = (fl >> 4) & 3;
      const float lst = (lidx == 0) ? cst0 : (lidx == 1) ? cst1 : (lidx == 2) ? cst2 : cst3;
      const float rst = (ridx == 0) ? cst0 : (ridx == 1) ? cst1 : (ridx == 2) ? cst2 : cst3;
      if (fl & 1) lcv = lst;
      if (fl & 2) rcv = rst;
    }
    // flag spin for left reduce child (advisory; windowed)
    if (fl & 1) {
      const unsigned int* fwp = fu + (unsigned)((s_lrx[r] & (FLAG_WIN - 1)) * 128);
      for (;;) {
        unsigned int d0 = __hip_atomic_load(fwp + l, __ATOMIC_RELAXED, __HIP_MEMORY_SCOPE_AGENT);
        unsigned int d1 = __hip_atomic_load(fwp + 64 + l, __ATOMIC_RELAXED, __HIP_MEMORY_SCOPE_AGENT);
        if (__all((d0 == 0x01010101u) && (d1 == 0x01010101u))) break;
        __builtin_amdgcn_s_sleep(1);
      }
    }
    // h acquisition (NaN backstop guarantees correctness)
    float hv[16];
    {
      const float* hrow = hs + (long long)ln * HDIM;
      if (fl & 1) {
        for (;;) {
          bool ready = true;
#pragma unroll
          for (int q = 0; q < 16; ++q) {
            unsigned int u = __hip_atomic_load((const unsigned int*)(hrow + q * 64 + l),
                                               __ATOMIC_RELAXED, __HIP_MEMORY_SCOPE_AGENT);
            ready = ready && (u != NAN_U);
            hv[q] = __uint_as_float(u);
          }
          if (__all(ready)) break;
          __builtin_amdgcn_s_sleep(1);
        }
      } else {
#pragma unroll
        for (int q = 0; q < 16; ++q) hv[q] = hrow[q * 64 + l];
      }
    }
    float acc[10];
#pragma unroll
    for (int k = 0; k < 10; ++k) acc[k] = 0.f;
#pragma unroll
    for (int k = 0; k < 10; ++k)
#pragma unroll
      for (int q = 0; q < 16; ++q) acc[k] = fmaf(wreg[k][q], hv[q], acc[k]);
    if (fl & 2) {  // right child is a reduce (never for comb data): stream W_rhh
      const unsigned int* fwp = fu + (unsigned)((s_rrx[r] & (FLAG_WIN - 1)) * 128);
      for (;;) {
        unsigned int d0 = __hip_atomic_load(fwp + l, __ATOMIC_RELAXED, __HIP_MEMORY_SCOPE_AGENT);
        unsigned int d1 = __hip_atomic_load(fwp + 64 + l, __ATOMIC_RELAXED, __HIP_MEMORY_SCOPE_AGENT);
        if (__all((d0 == 0x01010101u) && (d1 == 0x01010101u))) break;
        __builtin_amdgcn_s_sleep(1);
      }
      float hv2[16];
      const float* hrow2 = hs + (long long)rn * HDIM;
      for (;;) {
        bool ready = true;
#pragma unroll
        for (int q = 0; q < 16; ++q) {
          unsigned int u = __hip_atomic_load((const unsigned int*)(hrow2 + q * 64 + l),
                                             __ATOMIC_RELAXED, __HIP_MEMORY_SCOPE_AGENT);
          ready = ready && (u != NAN_U);
          hv2[q] = __uint_as_float(u);
        }
        if (__all(ready)) break;
        __builtin_amdgcn_s_sleep(1);
      }
#pragma unroll
      for (int c = 0; c < 2; ++c)
#pragma unroll
        for (int g = 0; g < 5; ++g) {
          const float* wp = Wr + (long long)(g * HDIM + ch0 + c) * HDIM + l;
#pragma unroll
          for (int q = 0; q < 16; ++q) acc[c * 5 + g] = fmaf(wp[q * 64], hv2[q], acc[c * 5 + g]);
        }
    }
    // in-wave butterfly: every lane ends with all 10 sums
#pragma unroll
    for (int k = 0; k < 10; ++k) {
      float v = acc[k];
      v += __shfl_xor(v, 32); v += __shfl_xor(v, 16); v += __shfl_xor(v, 8);
      v += __shfl_xor(v, 4);  v += __shfl_xor(v, 2);  v += __shfl_xor(v, 1);
      acc[k] = v;
    }
    float yh_l = 0.f, yc_l = 0.f;
    if (l < 2) {
      const float ai  = (l == 0) ? acc[0] : acc[5];
      const float alf = (l == 0) ? acc[1] : acc[6];
      const float arf = (l == 0) ? acc[2] : acc[7];
      const float ag  = (l == 0) ? acc[3] : acc[8];
      const float ao  = (l == 0) ? acc[4] : acc[9];
      const float ii = sigf(pv0 + ai), lf = sigf(pv1 + alf), rf = sigf(pv2 + arf);
      const float gv = tanh_f(pv3 + ag), oo = sigf(pv4 + ao);
      yc_l = lf * lcv + rf * rcv + ii * gv;
      yh_l = oo * tanh_f(yc_l);
    }
    {  // per-lane c-stack update (only lanes 0/1 meaningful)
      const int pos = (fl >> 6) & 3;
      cst0 = (pos == 0) ? yc_l : cst0;
      cst1 = (pos == 1) ? yc_l : cst1;
      cst2 = (pos == 2) ? yc_l : cst2;
      cst3 = (pos == 3) ? yc_l : cst3;
    }
    const float yh1 = __shfl(yh_l, 1);
    const float yc1 = __shfl(yc_l, 1);
    if (l == 0) {
      float2 c2; c2.x = yc_l; c2.y = yc1;
      *(float2*)(cs + (long long)t * HDIM + ch0) = c2;  // validation / leaf-read path
      unsigned long long pk = ((unsigned long long)__float_as_uint(yh1) << 32) |
                              (unsigned long long)__float_as_uint(yh_l);
      __hip_atomic_store((unsigned long long*)(hs + (long long)t * HDIM + ch0), pk,
                         __ATOMIC_RELAXED, __HIP_MEMORY_SCOPE_AGENT);
    }
    __asm__ volatile("s_waitcnt vmcnt(0)" ::: "memory");
    if (l == 0) {
      __hip_atomic_store(flags + (unsigned)((r & (FLAG_WIN - 1)) * 512 + wid),
                         (unsigned char)1, __ATOMIC_RELAXED, __HIP_MEMORY_SCOPE_AGENT);
    }
  }
}

__global__ void root_copy(float* __restrict__ out, const float* __restrict__ hs, int n_nodes) {
  int j = blockIdx.x * 256 + threadIdx.x;
  if (j < HDIM) out[j] = hs[(long long)(n_nodes - 1) * HDIM + j];
}

extern "C" void kernel_launch(void* const* d_in, const int* in_sizes, int n_in,
                              void* d_out, int out_size, void* d_ws, size_t ws_size,
                              hipStream_t stream) {
  const float* xs = (const float*)d_in[0];
  const int* ops = (const int*)d_in[1];
  const float* Wih = (const float*)d_in[2];
  const float* Wlhh = (const float*)d_in[3];
  const float* Wrhh = (const float*)d_in[4];
  const float* bih = (const float*)d_in[5];
  const float* blhh = (const float*)d_in[6];
  const float* brhh = (const float*)d_in[7];
  const int n_nodes = in_sizes[0] / HDIM;  // 4095

  char* ws = (char*)d_ws;
  float* wsf = (float*)d_ws;
  float* pre = (float*)(ws + PRE_OFF);
  float* leafg = (float*)(ws + LEAFG_OFF);
  unsigned short* xsbf = (unsigned short*)(ws + XSBF_OFF);
  unsigned short* wihb = (unsigned short*)(ws + WIH_OFF);
  unsigned short* wlhb = (unsigned short*)(ws + WLHH_OFF);
  unsigned short* wrhb = (unsigned short*)(ws + WRHH_OFF);
  unsigned short* hbf = (unsigned short*)(ws + HBF_OFF);
  float* b3 = (float*)(ws + B3_OFF);
  int* plan = (int*)(ws + PLAN_OFF);
  unsigned char* flags = (unsigned char*)(ws + FLAG_OFF);

  float* out = (float*)d_out;
  float* hs = out + HDIM;
  float* cs = hs + (long long)n_nodes * HDIM;

  hipLaunchKernelGGL(plan_kernel, dim3(1), dim3(256), 0, stream, ops, n_nodes, plan);
  hipLaunchKernelGGL(init_nan_kernel, dim3(n_nodes), dim3(256), 0, stream,
                     ops, n_nodes, (unsigned int*)hs);
  hipLaunchKernelGGL(cvt_bf16_kernel, dim3(4096), dim3(256), 0, stream,
                     xs, xsbf, 4096 * HDIM, n_nodes * HDIM);
  hipLaunchKernelGGL(cvt_bf16_kernel, dim3(5120), dim3(256), 0, stream,
                     Wih, wihb, GDIM * HDIM, GDIM * HDIM);
  hipLaunchKernelGGL(cvt_bf16_kernel, dim3(5120), dim3(256), 0, stream,
                     Wlhh, wlhb, GDIM * HDIM, GDIM * HDIM);
  hipLaunchKernelGGL(cvt_bf16_kernel, dim3(5120), dim3(256), 0, stream,
                     Wrhh, wrhb, GDIM * HDIM, GDIM * HDIM);
  hipLaunchKernelGGL(b3_kernel, dim3(20), dim3(256), 0, stream, bih, blhh, brhh, b3);
  // G1: ih projection for all nodes, scattered to leafg / pre rows, +b3
  hipLaunchKernelGGL((gemm_bt<0, 0>), dim3(32, 40), dim3(256), 0, stream,
                     xsbf, wihb, (const int*)nullptr, plan + P_DEST1, wsf, b3, plan + P_CNT + 3);
  hipLaunchKernelGGL(leaf_cell, dim3((n_nodes + 1) / 2), dim3(256), 0, stream,
                     leafg, plan, hs, cs, hbf);
  // G2R: += W_rhh @ h[leaf right children] ; G2L: += W_lhh @ h[leaf left children]
  hipLaunchKernelGGL((gemm_bt<1, 1>), dim3(16, 40), dim3(256), 0, stream,
                     hbf, wrhb, plan + P_NODER, plan + P_DESTR, wsf, (const float*)nullptr, plan + P_CNT + 1);
  hipLaunchKernelGGL((gemm_bt<1, 1>), dim3(16, 40), dim3(256), 0, stream,
                     hbf, wlhb, plan + P_NODEL, plan + P_DESTL, wsf, (const float*)nullptr, plan + P_CNT + 2);
  hipLaunchKernelGGL(serial_chain, dim3(NWG_SER), dim3(TPB_SER), 0, stream,
                     Wlhh, Wrhh, pre, plan, hs, cs, flags);
  hipLaunchKernelGGL(root_copy, dim3(4), dim3(256), 0, stream, out, hs, n_nodes);
}

// Round 6
// 10440.472 us; speedup vs baseline: 1.5564x; 1.5564x over previous
//
#include <hip/hip_runtime.h>
#include <hip/hip_bf16.h>
#include <stdint.h>

#define HDIM 1024
#define GDIM 5120
#define NWG_SER 64
#define TPB_SER 256
#define NAN_U 0x7FC00000u

typedef __attribute__((ext_vector_type(8))) short v8s;
typedef __attribute__((ext_vector_type(4))) float v4f;

// ---------------- workspace layout (bytes) ----------------
constexpr long long PRE_OFF   = 0;                              // f32 [2048][5120] gate pre-sums for reduces
constexpr long long LEAFG_OFF = PRE_OFF   + 2048LL * 5120 * 4;  // f32 [2048][5120] leaf gates
constexpr long long DUMP_OFF  = LEAFG_OFF + 2048LL * 5120 * 4;  // f32 [8192] scratch dump row
constexpr long long XSBF_OFF  = DUMP_OFF  + 8192LL * 4;         // bf16 [4096][1024]
constexpr long long WIH_OFF   = XSBF_OFF  + 4096LL * 1024 * 2;  // bf16 [5120][1024]
constexpr long long WLHH_OFF  = WIH_OFF   + 5120LL * 1024 * 2;
constexpr long long WRHH_OFF  = WLHH_OFF  + 5120LL * 1024 * 2;
constexpr long long HBF_OFF   = WRHH_OFF  + 5120LL * 1024 * 2;  // bf16 [4096][1024] per-node h (GEMM input)
constexpr long long B3_OFF    = HBF_OFF   + 4096LL * 1024 * 2;  // f32 [5120]
constexpr long long PLAN_OFF  = B3_OFF    + 5120LL * 4;         // int [26688]
// total ~126.2 MiB

// plan array offsets (int units)
constexpr int P_TRED = 0, P_LNODE = 2048, P_RNODE = 4096, P_FLAGS = 6144,
              P_TLEAF = 8192, P_DEST1 = 10240, P_NODER = 14336, P_DESTR = 16384,
              P_NODEL = 18432, P_DESTL = 20480, P_CNT = 22528,
              P_LRX = 22592, P_RRX = 24640;
// counts: [0]=nred, [1]=activeR rows, [2]=activeL rows, [3]=n_nodes (G1 active rows)
// FLAGS packing: bit0 = left child is reduce; bit1 = right child is reduce;
//                bits2-3 = lidx (stack slot), bits4-5 = ridx, bits6-7 = pos.

// f32-element bases inside ws
constexpr int PRE_E   = 0;
constexpr int LEAFG_E = (int)(LEAFG_OFF / 4);
constexpr int DUMP_E  = (int)(DUMP_OFF / 4);

static __device__ __forceinline__ float sigf(float x) { return 1.0f / (1.0f + __expf(-x)); }
static __device__ __forceinline__ float tanh_f(float x) {
  if (x > 15.0f) return 1.0f;
  if (x < -15.0f) return -1.0f;
  float e = __expf(2.0f * x);
  return (e - 1.0f) / (e + 1.0f);
}
static __device__ __forceinline__ unsigned short f2bf(float x) {
  __hip_bfloat16 h = __float2bfloat16(x);
  union { __hip_bfloat16 h; unsigned short u; } cv;
  cv.h = h;
  return cv.u;
}

// ---------------- plan: simulate the stack, build scatter lists ----------------
__global__ void plan_kernel(const int* __restrict__ ops, int n_nodes, int* __restrict__ plan) {
  __shared__ int sops[4096];
  __shared__ int red_of[4096];
  for (int i = threadIdx.x; i < n_nodes; i += 256) sops[i] = ops[i];
  __syncthreads();
  if (threadIdx.x != 0) return;
  int stack[4] = {0, 0, 0, 0};
  int ptr = 0, nred = 0, nleaf = 0, nR = 0, nL = 0;
  for (int t = 0; t < n_nodes; ++t) {
    int op = sops[t];
    if (op == 1) {
      int ridx = min(max(ptr - 1, 0), 3);
      int lidx = min(max(ptr - 2, 0), 3);
      int ln = stack[lidx], rn = stack[ridx];
      int r = nred++;
      plan[P_TRED + r] = t;
      plan[P_LNODE + r] = ln;
      plan[P_RNODE + r] = rn;
      int pos = min(max(ptr - 2, 0), 3);
      int lred = (sops[ln] == 1) ? 1 : 0;
      int rred = (sops[rn] == 1) ? 2 : 0;
      plan[P_FLAGS + r] = lred | rred | (lidx << 2) | (ridx << 4) | (pos << 6);
      plan[P_LRX + r] = lred ? red_of[ln] : 0;
      plan[P_RRX + r] = rred ? red_of[rn] : 0;
      plan[P_DEST1 + t] = PRE_E + r * GDIM;
      if (!rred) { plan[P_NODER + nR] = rn; plan[P_DESTR + nR] = PRE_E + r * GDIM; nR++; }
      if (!lred) { plan[P_NODEL + nL] = ln; plan[P_DESTL + nL] = PRE_E + r * GDIM; nL++; }
      red_of[t] = r;
      stack[pos] = t;
      ptr = (ptr - 2) + 1;
    } else {
      int li = nleaf++;
      plan[P_TLEAF + li] = t;
      plan[P_DEST1 + t] = LEAFG_E + li * GDIM;
      stack[min(max(ptr, 0), 3)] = t;
      ptr = ptr + 1;
    }
  }
  for (int i = n_nodes; i < 4096; ++i) plan[P_DEST1 + i] = DUMP_E;
  for (int i = nR; i < 2048; ++i) { plan[P_NODER + i] = 0; plan[P_DESTR + i] = DUMP_E; }
  for (int i = nL; i < 2048; ++i) { plan[P_NODEL + i] = 0; plan[P_DESTL + i] = DUMP_E; }
  plan[P_CNT + 0] = nred;
  plan[P_CNT + 1] = nR;
  plan[P_CNT + 2] = nL;
  plan[P_CNT + 3] = n_nodes;
}

// ---------------- NaN-sentinel init for reduce-node h rows ----------------
__global__ void init_nan_kernel(const int* __restrict__ ops, int n_nodes,
                                unsigned int* __restrict__ hsu) {
  const int t = blockIdx.x;
  if (t >= n_nodes || ops[t] != 1) return;
  uint4 nv = make_uint4(NAN_U, NAN_U, NAN_U, NAN_U);
  *(uint4*)(hsu + (long long)t * HDIM + threadIdx.x * 4) = nv;
}

// ---------------- f32 -> bf16 convert (zero-pads beyond nsrc) ----------------
__global__ void cvt_bf16_kernel(const float* __restrict__ src, unsigned short* __restrict__ dst,
                                int ntotal, int nsrc) {
  int i = (blockIdx.x * 256 + threadIdx.x) * 4;
  if (i >= ntotal) return;
  float4 v = make_float4(0.f, 0.f, 0.f, 0.f);
  if (i < nsrc) v = *(const float4*)(src + i);
  ushort4 o;
  o.x = f2bf(v.x); o.y = f2bf(v.y); o.z = f2bf(v.z); o.w = f2bf(v.w);
  *(ushort4*)(dst + i) = o;
}

__global__ void b3_kernel(const float* __restrict__ a, const float* __restrict__ b,
                          const float* __restrict__ c, float* __restrict__ o) {
  int i = blockIdx.x * 256 + threadIdx.x;
  if (i < GDIM) o[i] = a[i] + b[i] + c[i];
}

// ---------------- NT MFMA GEMM with per-row scatter destinations ----------------
template <int GATHER, int ACCUM>
__global__ __launch_bounds__(256, 1) void gemm_bt(
    const unsigned short* __restrict__ A, const unsigned short* __restrict__ B,
    const int* __restrict__ gidx, const int* __restrict__ dest,
    float* __restrict__ wsf, const float* __restrict__ b3,
    const int* __restrict__ activeRows) {
  if ((int)blockIdx.x * 128 >= *activeRows) return;
  __shared__ unsigned short As[128 * 32];
  __shared__ unsigned short Bs[128 * 32];
  const int tid = threadIdx.x;
  const int w = tid >> 6, l = tid & 63;
  const int tm = blockIdx.x, tn = blockIdx.y;
  const int q0 = w * 2, q1 = w * 2 + 1;
  const int r0 = q0 * 16 + (l >> 2), r1 = q1 * 16 + (l >> 2);
  const int ck = (l & 3) * 8;
  int ga0 = tm * 128 + r0, ga1 = tm * 128 + r1;
  if (GATHER) { ga0 = gidx[ga0]; ga1 = gidx[ga1]; }
  const unsigned short* ap0 = A + (long long)ga0 * HDIM + ck;
  const unsigned short* ap1 = A + (long long)ga1 * HDIM + ck;
  const unsigned short* bp0 = B + (long long)(tn * 128 + r0) * HDIM + ck;
  const unsigned short* bp1 = B + (long long)(tn * 128 + r1) * HDIM + ck;
  uint4* asd0 = (uint4*)(As + q0 * 512) + l;
  uint4* asd1 = (uint4*)(As + q1 * 512) + l;
  uint4* bsd0 = (uint4*)(Bs + q0 * 512) + l;
  uint4* bsd1 = (uint4*)(Bs + q1 * 512) + l;
  const int wr = w >> 1, wc = w & 1;
  const int lrow = l & 15, lq = l >> 4;
  const unsigned short* Ard = As + (wr * 64 + lrow) * 32 + lq * 8;
  const unsigned short* Brd = Bs + (wc * 64 + lrow) * 32 + lq * 8;
  v4f acc[4][4];
#pragma unroll
  for (int m = 0; m < 4; ++m)
#pragma unroll
    for (int n = 0; n < 4; ++n) acc[m][n] = (v4f){0.f, 0.f, 0.f, 0.f};
  for (int kb = 0; kb < 32; ++kb) {
    const int ko = kb * 32;
    uint4 a0 = *(const uint4*)(ap0 + ko);
    uint4 a1 = *(const uint4*)(ap1 + ko);
    uint4 b0 = *(const uint4*)(bp0 + ko);
    uint4 b1 = *(const uint4*)(bp1 + ko);
    __syncthreads();
    *asd0 = a0; *asd1 = a1; *bsd0 = b0; *bsd1 = b1;
    __syncthreads();
    v8s af[4], bfr[4];
#pragma unroll
    for (int m = 0; m < 4; ++m) af[m] = *(const v8s*)(Ard + m * 512);
#pragma unroll
    for (int n = 0; n < 4; ++n) bfr[n] = *(const v8s*)(Brd + n * 512);
#pragma unroll
    for (int m = 0; m < 4; ++m)
#pragma unroll
      for (int n = 0; n < 4; ++n)
        acc[m][n] = __builtin_amdgcn_mfma_f32_16x16x32_bf16(af[m], bfr[n], acc[m][n], 0, 0, 0);
  }
#pragma unroll
  for (int m = 0; m < 4; ++m) {
#pragma unroll
    for (int jj = 0; jj < 4; ++jj) {
      const int arow = tm * 128 + wr * 64 + m * 16 + lq * 4 + jj;
      const int doff = dest[arow];
#pragma unroll
      for (int n = 0; n < 4; ++n) {
        const int col = tn * 128 + wc * 64 + n * 16 + lrow;
        float v = acc[m][n][jj];
        if (ACCUM) wsf[doff + col] += v;
        else wsf[doff + col] = v + b3[col];
      }
    }
  }
}

// ---------------- leaf (shift) cell: gates -> h,c with zero hidden state ----------------
__global__ void leaf_cell(const float* __restrict__ leafg, const int* __restrict__ plan,
                          float* __restrict__ hs, float* __restrict__ cs,
                          unsigned short* __restrict__ hbf) {
  const int li = blockIdx.x;
  const int j = threadIdx.x * 4;
  const float* row = leafg + (long long)li * GDIM;
  float4 gi = *(const float4*)(row + j);
  float4 gg = *(const float4*)(row + 3 * HDIM + j);
  float4 go = *(const float4*)(row + 4 * HDIM + j);
  const int t = plan[P_TLEAF + li];
  float4 yc, yh;
  yc.x = sigf(gi.x) * tanh_f(gg.x); yc.y = sigf(gi.y) * tanh_f(gg.y);
  yc.z = sigf(gi.z) * tanh_f(gg.z); yc.w = sigf(gi.w) * tanh_f(gg.w);
  yh.x = sigf(go.x) * tanh_f(yc.x); yh.y = sigf(go.y) * tanh_f(yc.y);
  yh.z = sigf(go.z) * tanh_f(yc.z); yh.w = sigf(go.w) * tanh_f(yc.w);
  *(float4*)(hs + (long long)t * HDIM + j) = yh;
  *(float4*)(cs + (long long)t * HDIM + j) = yc;
  ushort4 hb;
  hb.x = f2bf(yh.x); hb.y = f2bf(yh.y); hb.z = f2bf(yh.z); hb.w = f2bf(yh.w);
  *(ushort4*)(hbf + (long long)t * HDIM + j) = hb;
}

// ---------------- serial reduce chain v6: direct NaN-data-poll, wave-autonomous ----------------
// 64 WGs x 256 threads = 256 waves. Wave owns 4 channels (20 f32 weight rows in
// registers; lane l holds h columns {128p + 2l, +1}). Protocol = R3's direct
// data poll (the detecting load IS the data); zero barriers / LDS / flags /
// extra hops in the loop. Butterfly reduce in-wave; cell in lanes 0-3;
// c-stack in registers; h written as two 8B agent stores.
__global__ __launch_bounds__(TPB_SER, 1) void serial_chain(
    const float* __restrict__ Wl, const float* __restrict__ Wr,
    const float* __restrict__ pre, const int* __restrict__ plan,
    float* __restrict__ hs, float* __restrict__ cs) {
  const int wg = blockIdx.x;
  const int tid = threadIdx.x;
  const int w = tid >> 6, l = tid & 63;
  const int ch0 = (wg * 4 + w) * 4;  // 4 channels per wave
  __shared__ int s_t[2048], s_ln[2048], s_rn[2048], s_fl[2048];
  const int nred = plan[P_CNT + 0];
  for (int i = tid; i < nred; i += TPB_SER) {
    s_t[i] = plan[P_TRED + i];
    s_ln[i] = plan[P_LNODE + i];
    s_rn[i] = plan[P_RNODE + i];
    s_fl[i] = plan[P_FLAGS + i];
  }
  // weights: k = c*5 + g -> row g*1024 + ch0 + c; lane l holds cols 128p+2l(+1)
  float wreg[20][16];
#pragma unroll
  for (int c = 0; c < 4; ++c)
#pragma unroll
    for (int g = 0; g < 5; ++g) {
      const float* wp = Wl + (long long)(g * HDIM + ch0 + c) * HDIM + 2 * l;
#pragma unroll
      for (int p = 0; p < 8; ++p) {
        float2 v = *(const float2*)(wp + p * 128);
        wreg[c * 5 + g][2 * p] = v.x;
        wreg[c * 5 + g][2 * p + 1] = v.y;
      }
    }
  float cst0 = 0.f, cst1 = 0.f, cst2 = 0.f, cst3 = 0.f;  // per-lane c stack (lanes 0-3)
  __syncthreads();
  for (int r = 0; r < nred; ++r) {
    const int t = s_t[r], ln = s_ln[r], rn = s_rn[r], fl = s_fl[r];
    // early-issue: pre slice + leaf-child c (latency hides under the poll)
    float pv0 = 0.f, pv1 = 0.f, pv2 = 0.f, pv3 = 0.f, pv4 = 0.f, lcv = 0.f, rcv = 0.f;
    if (l < 4) {
      const float* pr = pre + (long long)r * GDIM + ch0 + l;
      pv0 = pr[0]; pv1 = pr[HDIM]; pv2 = pr[2 * HDIM]; pv3 = pr[3 * HDIM]; pv4 = pr[4 * HDIM];
      if (!(fl & 1)) lcv = cs[(long long)ln * HDIM + ch0 + l];
      if (!(fl & 2)) rcv = cs[(long long)rn * HDIM + ch0 + l];
    }
    {
      const int lidx = (fl >> 2) & 3, ridx = (fl >> 4) & 3;
      const float lst = (lidx == 0) ? cst0 : (lidx == 1) ? cst1 : (lidx == 2) ? cst2 : cst3;
      const float rst = (ridx == 0) ? cst0 : (ridx == 1) ? cst1 : (ridx == 2) ? cst2 : cst3;
      if (fl & 1) lcv = lst;
      if (fl & 2) rcv = rst;
    }
    // h acquisition: the polling load delivers the data (NaN = not ready)
    float hv[16];
    {
      const float* hrow = hs + (long long)ln * HDIM;
      if (fl & 1) {
        const unsigned long long* h8 = (const unsigned long long*)hrow;
        for (;;) {
          bool ready = true;
          unsigned long long u[8];
#pragma unroll
          for (int p = 0; p < 8; ++p) {
            u[p] = __hip_atomic_load(h8 + p * 64 + l, __ATOMIC_RELAXED, __HIP_MEMORY_SCOPE_AGENT);
            ready = ready && ((unsigned int)u[p] != NAN_U) && ((unsigned int)(u[p] >> 32) != NAN_U);
          }
          if (__all(ready)) {
#pragma unroll
            for (int p = 0; p < 8; ++p) {
              hv[2 * p]     = __uint_as_float((unsigned int)u[p]);
              hv[2 * p + 1] = __uint_as_float((unsigned int)(u[p] >> 32));
            }
            break;
          }
        }
      } else {
#pragma unroll
        for (int p = 0; p < 8; ++p) {
          float2 v = *(const float2*)(hrow + p * 128 + 2 * l);
          hv[2 * p] = v.x; hv[2 * p + 1] = v.y;
        }
      }
    }
    float acc[20];
#pragma unroll
    for (int k = 0; k < 20; ++k) acc[k] = 0.f;
#pragma unroll
    for (int k = 0; k < 20; ++k)
#pragma unroll
      for (int q = 0; q < 16; ++q) acc[k] = fmaf(wreg[k][q], hv[q], acc[k]);
    if (fl & 2) {  // right child is a reduce (never for comb data): stream W_rhh
      float hv2[16];
      const unsigned long long* h8 = (const unsigned long long*)(hs + (long long)rn * HDIM);
      for (;;) {
        bool ready = true;
        unsigned long long u[8];
#pragma unroll
        for (int p = 0; p < 8; ++p) {
          u[p] = __hip_atomic_load(h8 + p * 64 + l, __ATOMIC_RELAXED, __HIP_MEMORY_SCOPE_AGENT);
          ready = ready && ((unsigned int)u[p] != NAN_U) && ((unsigned int)(u[p] >> 32) != NAN_U);
        }
        if (__all(ready)) {
#pragma unroll
          for (int p = 0; p < 8; ++p) {
            hv2[2 * p]     = __uint_as_float((unsigned int)u[p]);
            hv2[2 * p + 1] = __uint_as_float((unsigned int)(u[p] >> 32));
          }
          break;
        }
      }
#pragma unroll
      for (int c = 0; c < 4; ++c)
#pragma unroll
        for (int g = 0; g < 5; ++g) {
          const float* wp = Wr + (long long)(g * HDIM + ch0 + c) * HDIM + 2 * l;
#pragma unroll
          for (int p = 0; p < 8; ++p) {
            float2 v = *(const float2*)(wp + p * 128);
            acc[c * 5 + g] = fmaf(v.x, hv2[2 * p], acc[c * 5 + g]);
            acc[c * 5 + g] = fmaf(v.y, hv2[2 * p + 1], acc[c * 5 + g]);
          }
        }
    }
    // in-wave butterfly: every lane ends with all 20 sums
#pragma unroll
    for (int k = 0; k < 20; ++k) {
      float v = acc[k];
      v += __shfl_xor(v, 32); v += __shfl_xor(v, 16); v += __shfl_xor(v, 8);
      v += __shfl_xor(v, 4);  v += __shfl_xor(v, 2);  v += __shfl_xor(v, 1);
      acc[k] = v;
    }
    float yh_l = 0.f, yc_l = 0.f;
    if (l < 4) {
      const float ai  = (l == 0) ? acc[0] : (l == 1) ? acc[5]  : (l == 2) ? acc[10] : acc[15];
      const float alf = (l == 0) ? acc[1] : (l == 1) ? acc[6]  : (l == 2) ? acc[11] : acc[16];
      const float arf = (l == 0) ? acc[2] : (l == 1) ? acc[7]  : (l == 2) ? acc[12] : acc[17];
      const float ag  = (l == 0) ? acc[3] : (l == 1) ? acc[8]  : (l == 2) ? acc[13] : acc[18];
      const float ao  = (l == 0) ? acc[4] : (l == 1) ? acc[9]  : (l == 2) ? acc[14] : acc[19];
      const float ii = sigf(pv0 + ai), lf = sigf(pv1 + alf), rf = sigf(pv2 + arf);
      const float gv = tanh_f(pv3 + ag), oo = sigf(pv4 + ao);
      yc_l = lf * lcv + rf * rcv + ii * gv;
      yh_l = oo * tanh_f(yc_l);
    }
    {  // per-lane c-stack update (lanes 0-3 hold real values)
      const int pos = (fl >> 6) & 3;
      cst0 = (pos == 0) ? yc_l : cst0;
      cst1 = (pos == 1) ? yc_l : cst1;
      cst2 = (pos == 2) ? yc_l : cst2;
      cst3 = (pos == 3) ? yc_l : cst3;
    }
    const float yhn = __shfl_xor(yh_l, 1);  // lane0<->1, lane2<->3
    const float ycn = __shfl_xor(yc_l, 1);
    if (l == 0 || l == 2) {
      float2 c2; c2.x = yc_l; c2.y = ycn;
      *(float2*)(cs + (long long)t * HDIM + ch0 + l) = c2;  // intra-wave reuse via regs; this is for validation
      unsigned long long pk = ((unsigned long long)__float_as_uint(yhn) << 32) |
                              (unsigned long long)__float_as_uint(yh_l);
      __hip_atomic_store((unsigned long long*)(hs + (long long)t * HDIM + ch0 + l), pk,
                         __ATOMIC_RELAXED, __HIP_MEMORY_SCOPE_AGENT);
    }
  }
}

__global__ void root_copy(float* __restrict__ out, const float* __restrict__ hs, int n_nodes) {
  int j = blockIdx.x * 256 + threadIdx.x;
  if (j < HDIM) out[j] = hs[(long long)(n_nodes - 1) * HDIM + j];
}

extern "C" void kernel_launch(void* const* d_in, const int* in_sizes, int n_in,
                              void* d_out, int out_size, void* d_ws, size_t ws_size,
                              hipStream_t stream) {
  const float* xs = (const float*)d_in[0];
  const int* ops = (const int*)d_in[1];
  const float* Wih = (const float*)d_in[2];
  const float* Wlhh = (const float*)d_in[3];
  const float* Wrhh = (const float*)d_in[4];
  const float* bih = (const float*)d_in[5];
  const float* blhh = (const float*)d_in[6];
  const float* brhh = (const float*)d_in[7];
  const int n_nodes = in_sizes[0] / HDIM;  // 4095

  char* ws = (char*)d_ws;
  float* wsf = (float*)d_ws;
  float* pre = (float*)(ws + PRE_OFF);
  float* leafg = (float*)(ws + LEAFG_OFF);
  unsigned short* xsbf = (unsigned short*)(ws + XSBF_OFF);
  unsigned short* wihb = (unsigned short*)(ws + WIH_OFF);
  unsigned short* wlhb = (unsigned short*)(ws + WLHH_OFF);
  unsigned short* wrhb = (unsigned short*)(ws + WRHH_OFF);
  unsigned short* hbf = (unsigned short*)(ws + HBF_OFF);
  float* b3 = (float*)(ws + B3_OFF);
  int* plan = (int*)(ws + PLAN_OFF);

  float* out = (float*)d_out;
  float* hs = out + HDIM;
  float* cs = hs + (long long)n_nodes * HDIM;

  hipLaunchKernelGGL(plan_kernel, dim3(1), dim3(256), 0, stream, ops, n_nodes, plan);
  hipLaunchKernelGGL(init_nan_kernel, dim3(n_nodes), dim3(256), 0, stream,
                     ops, n_nodes, (unsigned int*)hs);
  hipLaunchKernelGGL(cvt_bf16_kernel, dim3(4096), dim3(256), 0, stream,
                     xs, xsbf, 4096 * HDIM, n_nodes * HDIM);
  hipLaunchKernelGGL(cvt_bf16_kernel, dim3(5120), dim3(256), 0, stream,
                     Wih, wihb, GDIM * HDIM, GDIM * HDIM);
  hipLaunchKernelGGL(cvt_bf16_kernel, dim3(5120), dim3(256), 0, stream,
                     Wlhh, wlhb, GDIM * HDIM, GDIM * HDIM);
  hipLaunchKernelGGL(cvt_bf16_kernel, dim3(5120), dim3(256), 0, stream,
                     Wrhh, wrhb, GDIM * HDIM, GDIM * HDIM);
  hipLaunchKernelGGL(b3_kernel, dim3(20), dim3(256), 0, stream, bih, blhh, brhh, b3);
  // G1: ih projection for all nodes, scattered to leafg / pre rows, +b3
  hipLaunchKernelGGL((gemm_bt<0, 0>), dim3(32, 40), dim3(256), 0, stream,
                     xsbf, wihb, (const int*)nullptr, plan + P_DEST1, wsf, b3, plan + P_CNT + 3);
  hipLaunchKernelGGL(leaf_cell, dim3((n_nodes + 1) / 2), dim3(256), 0, stream,
                     leafg, plan, hs, cs, hbf);
  // G2R: += W_rhh @ h[leaf right children] ; G2L: += W_lhh @ h[leaf left children]
  hipLaunchKernelGGL((gemm_bt<1, 1>), dim3(16, 40), dim3(256), 0, stream,
                     hbf, wrhb, plan + P_NODER, plan + P_DESTR, wsf, (const float*)nullptr, plan + P_CNT + 1);
  hipLaunchKernelGGL((gemm_bt<1, 1>), dim3(16, 40), dim3(256), 0, stream,
                     hbf, wlhb, plan + P_NODEL, plan + P_DESTL, wsf, (const float*)nullptr, plan + P_CNT + 2);
  hipLaunchKernelGGL(serial_chain, dim3(NWG_SER), dim3(TPB_SER), 0, stream,
                     Wlhh, Wrhh, pre, plan, hs, cs);
  hipLaunchKernelGGL(root_copy, dim3(4), dim3(256), 0, stream, out, hs, n_nodes);
}